// Round 4
// baseline (202.494 us; speedup 1.0000x reference)
//
#include <hip/hip_runtime.h>
#include <math.h>

// GraphLearner: per-edge cosine similarity + sigmoid + straight-through threshold.
//   out[e] = let v = sigmoid(cos(f1,f2)/T) in (v <= 0.5 ? 0 : v)
//
// R4 design:
//  - Kernel 1 (unchanged from R3): per-node clamped norm with numpy stride-8
//    pairwise accumulator order — proven BIT-EXACT vs np reference (R2 absmax=0.0).
//  - Kernel 2: 8 lanes per edge-PAIR group. Each group handles 2 edges:
//    one int2 index load per endpoint row covers both edges, then all 8 row
//    loads (4 per edge) issue with no intervening dependency -> 64 cache lines
//    in flight per wave (vs 32 in R3). Theory: the ~3.7 TB/s L2-miss fill rate
//    is a latency-queueing equilibrium, not a hard ceiling; 2x MLP pushes it.
//    8 lanes still cover each 128 B half-row line in ONE instruction (minimal
//    TA line requests). Epilogue on lanes 0/1, adjacent 4 B stores.

#define D 64
#define BLOCK 256
#define COS_EPS 1e-6f

#define FMA4(A, X, Y) \
    A.x += X.x * Y.x; A.y += X.y * Y.y; A.z += X.z * Y.z; A.w += X.w * Y.w;

// numpy pairwise_sum combination for 8 stride-8 accumulators packed as two float4s
#define PAIRWISE8(E, O) \
    (((E.x + E.y) + (E.z + E.w)) + ((O.x + O.y) + (O.z + O.w)))

__device__ __forceinline__ float read_temperature(const int* temp_ptr) {
    int tbits = *temp_ptr;
    if (tbits >= 1 && tbits < (1 << 23)) return (float)tbits;  // int32 temperature
    union { int i; float f; } u; u.i = tbits; return u.f;      // float32 bits
}

// Kernel 1: per-node clamped norm, numpy accumulation order (bit-exact).
__global__ __launch_bounds__(BLOCK) void node_norm_kernel(
    const float* __restrict__ node_embs,
    float*       __restrict__ dnorm,
    int n_nodes)
{
    int n = blockIdx.x * BLOCK + threadIdx.x;
    if (n >= n_nodes) return;

    const float4* __restrict__ r = (const float4*)(node_embs + (size_t)n * D);
    float4 z = make_float4(0.f, 0.f, 0.f, 0.f);
    float4 aE = z, aO = z;   // stride-8 accumulators r0..r3 / r4..r7 (numpy order)
    #pragma unroll
    for (int k = 0; k < D / 4; k += 2) {
        float4 x0 = r[k];
        float4 x1 = r[k + 1];
        FMA4(aE, x0, x0)
        FMA4(aO, x1, x1)
    }
    float s = PAIRWISE8(aE, aO);
    dnorm[n] = fmaxf(sqrtf(s), COS_EPS);
}

// Kernel 2: 8 lanes per group, 2 edges per group.
__global__ __launch_bounds__(BLOCK) void GraphLearner_68513318306086_kernel(
    const float* __restrict__ node_embs,
    const int*   __restrict__ edge_index,
    const float* __restrict__ dnorm,
    const int*   __restrict__ temp_ptr,
    float*       __restrict__ out,
    int n_edges)
{
    int t    = blockIdx.x * BLOCK + threadIdx.x;
    int g    = t >> 3;              // group id: handles edges 2g, 2g+1
    int lane = threadIdx.x & 7;
    int e0   = g * 2;
    if (e0 >= n_edges) return;
    bool has1 = (e0 + 1) < n_edges;

    // Index loads: one int2 per endpoint row covers both edges (8 B aligned:
    // e0 is even and n_edges=2M is even in this workload).
    int2 i0p, i1p;
    if (has1) {
        i0p = *(const int2*)(edge_index + e0);             // row 0: i0(e0), i0(e1)
        i1p = *(const int2*)(edge_index + n_edges + e0);   // row 1: i1(e0), i1(e1)
    } else {
        i0p.x = edge_index[e0];            i0p.y = i0p.x;
        i1p.x = edge_index[n_edges + e0];  i1p.y = i1p.x;
    }

    const float4* __restrict__ A0 = (const float4*)(node_embs + (size_t)i0p.x * D);
    const float4* __restrict__ B0 = (const float4*)(node_embs + (size_t)i1p.x * D);
    const float4* __restrict__ A1 = (const float4*)(node_embs + (size_t)i0p.y * D);
    const float4* __restrict__ B1 = (const float4*)(node_embs + (size_t)i1p.y * D);

    // All 8 row loads issue back-to-back: 64 lines in flight per wave.
    float4 a0l = A0[lane]; float4 a0h = A0[lane + 8];
    float4 b0l = B0[lane]; float4 b0h = B0[lane + 8];
    float4 a1l = A1[lane]; float4 a1h = A1[lane + 8];
    float4 b1l = B1[lane]; float4 b1h = B1[lane + 8];

    float p0 = ((a0l.x * b0l.x + a0l.y * b0l.y) + (a0l.z * b0l.z + a0l.w * b0l.w))
             + ((a0h.x * b0h.x + a0h.y * b0h.y) + (a0h.z * b0h.z + a0h.w * b0h.w));
    float p1 = ((a1l.x * b1l.x + a1l.y * b1l.y) + (a1l.z * b1l.z + a1l.w * b1l.w))
             + ((a1h.x * b1h.x + a1h.y * b1h.y) + (a1h.z * b1h.z + a1h.w * b1h.w));

    // 3-level xor tree across the 8-lane group (both edges in parallel)
    #pragma unroll
    for (int m = 1; m < 8; m <<= 1) {
        p0 += __shfl_xor(p0, m, 8);
        p1 += __shfl_xor(p1, m, 8);
    }

    if (lane < 2) {
        int   e = e0 + lane;
        if (lane == 0 || has1) {
            int   i0 = lane ? i0p.y : i0p.x;
            int   i1 = lane ? i1p.y : i1p.x;
            float p  = lane ? p1 : p0;
            float T  = read_temperature(temp_ptr);
            float cosv = p / (dnorm[i0] * dnorm[i1]);
            float v    = 1.0f / (1.0f + expf(-(cosv / T)));
            out[e] = (v <= 0.5f) ? 0.0f : v;    // straight-through hard threshold
        }
    }
}

// Fallback (ws too small for dnorm): 8 lanes/edge, inline norms (R3 fallback).
__global__ __launch_bounds__(BLOCK) void edge_kernel_fused(
    const float* __restrict__ node_embs,
    const int*   __restrict__ edge_index,
    const int*   __restrict__ temp_ptr,
    float*       __restrict__ out,
    int n_edges)
{
    int t    = blockIdx.x * BLOCK + threadIdx.x;
    int e    = t >> 3;
    int lane = threadIdx.x & 7;
    if (e >= n_edges) return;

    int i0 = edge_index[e];
    int i1 = edge_index[n_edges + e];

    const float4* __restrict__ r0 = (const float4*)(node_embs + (size_t)i0 * D);
    const float4* __restrict__ r1 = (const float4*)(node_embs + (size_t)i1 * D);

    float4 x0 = r0[lane];
    float4 x1 = r0[lane + 8];
    float4 y0 = r1[lane];
    float4 y1 = r1[lane + 8];

    float p  = ((x0.x * y0.x + x0.y * y0.y) + (x0.z * y0.z + x0.w * y0.w))
             + ((x1.x * y1.x + x1.y * y1.y) + (x1.z * y1.z + x1.w * y1.w));
    float a  = ((x0.x * x0.x + x0.y * x0.y) + (x0.z * x0.z + x0.w * x0.w))
             + ((x1.x * x1.x + x1.y * x1.y) + (x1.z * x1.z + x1.w * x1.w));
    float b  = ((y0.x * y0.x + y0.y * y0.y) + (y0.z * y0.z + y0.w * y0.w))
             + ((y1.x * y1.x + y1.y * y1.y) + (y1.z * y1.z + y1.w * y1.w));

    #pragma unroll
    for (int m = 1; m < 8; m <<= 1) {
        p += __shfl_xor(p, m, 8);
        a += __shfl_xor(a, m, 8);
        b += __shfl_xor(b, m, 8);
    }

    if (lane == 0) {
        float T    = read_temperature(temp_ptr);
        float d1   = fmaxf(sqrtf(a), COS_EPS);
        float d2   = fmaxf(sqrtf(b), COS_EPS);
        float cosv = p / (d1 * d2);
        float v    = 1.0f / (1.0f + expf(-(cosv / T)));
        out[e] = (v <= 0.5f) ? 0.0f : v;
    }
}

extern "C" void kernel_launch(void* const* d_in, const int* in_sizes, int n_in,
                              void* d_out, int out_size, void* d_ws, size_t ws_size,
                              hipStream_t stream) {
    const float* node_embs  = (const float*)d_in[0];
    const int*   edge_index = (const int*)d_in[1];
    const int*   temp_ptr   = (const int*)d_in[2];
    float*       out        = (float*)d_out;

    int n_nodes = in_sizes[0] / D;      // node_embs is [N, 64]
    int n_edges = in_sizes[1] / 2;      // edge_index is [2, E]

    if (ws_size >= (size_t)n_nodes * sizeof(float)) {
        float* dnorm = (float*)d_ws;
        int grid_n = (n_nodes + BLOCK - 1) / BLOCK;
        node_norm_kernel<<<grid_n, BLOCK, 0, stream>>>(node_embs, dnorm, n_nodes);

        int n_groups = (n_edges + 1) / 2;          // 2 edges per 8-lane group
        long long n_threads = (long long)n_groups * 8;
        int grid_e = (int)((n_threads + BLOCK - 1) / BLOCK);
        GraphLearner_68513318306086_kernel<<<grid_e, BLOCK, 0, stream>>>(
            node_embs, edge_index, dnorm, temp_ptr, out, n_edges);
    } else {
        int grid_e = (int)(((long long)n_edges * 8 + BLOCK - 1) / BLOCK);
        edge_kernel_fused<<<grid_e, BLOCK, 0, stream>>>(
            node_embs, edge_index, temp_ptr, out, n_edges);
    }
}

// Round 5
// 155.975 us; speedup vs baseline: 1.2982x; 1.2982x over previous
//
#include <hip/hip_runtime.h>
#include <hip/hip_fp16.h>
#include <math.h>

// GraphLearner: per-edge cosine similarity + sigmoid + straight-through threshold.
//   out[e] = let v = sigmoid(cos(f1,f2)/T) in (v <= 0.5 ? 0 : v)
//
// R5 design (R4 post-mortem: edge kernel is L2-miss-fill-throughput bound at
// ~3.6 TB/s with 440 MB fill; MLP doubling was a no-op. Only fewer bytes help):
//  - Kernel Q: quantize node_embs fp32 -> fp16 table in d_ws (25.6 -> 12.8 MB).
//    Row becomes 128 B = ONE cache line; gather demand halves and per-XCD L2
//    residency fraction doubles.
//  - Kernel N: per-node clamped fp32 norm, numpy stride-8 pairwise order —
//    BIT-EXACT vs np reference (proven by R2 absmax=0.0). Unchanged.
//  - Kernel E: 8 lanes/edge. Lane loads one 16 B chunk (8 halves) of each row;
//    dot via v_dot2_f32_f16 (fp16 mul exact in fp32, fp32 accumulate), 3-level
//    xor allreduce. Worst-case cos error <= ~1.3e-3; if |cos| < TAU=6e-3 the
//    group recomputes the edge in fp32 EXACTLY as R3 did (bit-identical path).
//    Expected fallback ~3.8% of edges.

#define D 64
#define BLOCK 256
#define COS_EPS 1e-6f
#define TAU 6e-3f

#define FMA4(A, X, Y) \
    A.x += X.x * Y.x; A.y += X.y * Y.y; A.z += X.z * Y.z; A.w += X.w * Y.w;

#define PAIRWISE8(E, O) \
    (((E.x + E.y) + (E.z + E.w)) + ((O.x + O.y) + (O.z + O.w)))

typedef _Float16 half2_t __attribute__((ext_vector_type(2)));

__device__ __forceinline__ half2_t as_h2(unsigned u) {
    union { unsigned u; half2_t v; } c; c.u = u; return c.v;
}

__device__ __forceinline__ float dot8_f16(uint4 A, uint4 B, float acc) {
#if __has_builtin(__builtin_amdgcn_fdot2)
    acc = __builtin_amdgcn_fdot2(as_h2(A.x), as_h2(B.x), acc, false);
    acc = __builtin_amdgcn_fdot2(as_h2(A.y), as_h2(B.y), acc, false);
    acc = __builtin_amdgcn_fdot2(as_h2(A.z), as_h2(B.z), acc, false);
    acc = __builtin_amdgcn_fdot2(as_h2(A.w), as_h2(B.w), acc, false);
#else
    const __half2* a = (const __half2*)&A;
    const __half2* b = (const __half2*)&B;
    #pragma unroll
    for (int i = 0; i < 4; ++i) {
        float2 af = __half22float2(a[i]);
        float2 bf = __half22float2(b[i]);
        acc = fmaf(af.x, bf.x, acc);
        acc = fmaf(af.y, bf.y, acc);
    }
#endif
    return acc;
}

__device__ __forceinline__ float read_temperature(const int* temp_ptr) {
    int tbits = *temp_ptr;
    if (tbits >= 1 && tbits < (1 << 23)) return (float)tbits;  // int32 temperature
    union { int i; float f; } u; u.i = tbits; return u.f;      // float32 bits
}

// Kernel Q: fp32 -> fp16 table. One thread per 8 consecutive elements.
__global__ __launch_bounds__(BLOCK) void quant_kernel(
    const float* __restrict__ in,
    __half*      __restrict__ htab,
    int n_elems)
{
    int t = blockIdx.x * BLOCK + threadIdx.x;
    int base = t * 8;
    if (base >= n_elems) return;
    const float4* p = (const float4*)(in + base);
    float4 a = p[0];
    float4 b = p[1];
    __half2 h[4];
    h[0] = __floats2half2_rn(a.x, a.y);
    h[1] = __floats2half2_rn(a.z, a.w);
    h[2] = __floats2half2_rn(b.x, b.y);
    h[3] = __floats2half2_rn(b.z, b.w);
    *(uint4*)(htab + base) = *(const uint4*)h;
}

// Kernel N: per-node clamped norm, numpy accumulation order (bit-exact).
__global__ __launch_bounds__(BLOCK) void node_norm_kernel(
    const float* __restrict__ node_embs,
    float*       __restrict__ dnorm,
    int n_nodes)
{
    int n = blockIdx.x * BLOCK + threadIdx.x;
    if (n >= n_nodes) return;

    const float4* __restrict__ r = (const float4*)(node_embs + (size_t)n * D);
    float4 z = make_float4(0.f, 0.f, 0.f, 0.f);
    float4 aE = z, aO = z;   // stride-8 accumulators (numpy pairwise order)
    #pragma unroll
    for (int k = 0; k < D / 4; k += 2) {
        float4 x0 = r[k];
        float4 x1 = r[k + 1];
        FMA4(aE, x0, x0)
        FMA4(aO, x1, x1)
    }
    float s = PAIRWISE8(aE, aO);
    dnorm[n] = fmaxf(sqrtf(s), COS_EPS);
}

// Kernel E: 8 lanes/edge, fp16 gather + fp32 borderline fallback.
__global__ __launch_bounds__(BLOCK) void GraphLearner_68513318306086_kernel(
    const float* __restrict__ node_embs,
    const __half* __restrict__ htab,
    const int*   __restrict__ edge_index,
    const float* __restrict__ dnorm,
    const int*   __restrict__ temp_ptr,
    float*       __restrict__ out,
    int n_edges)
{
    int t    = blockIdx.x * BLOCK + threadIdx.x;
    int e    = t >> 3;              // 8 lanes per edge
    int lane = threadIdx.x & 7;
    if (e >= n_edges) return;

    int i0 = edge_index[e];
    int i1 = edge_index[n_edges + e];

    // fp16 row = 128 B = one cache line; lane loads chunk `lane` (16 B).
    const uint4* __restrict__ rA = (const uint4*)(htab + i0 * D);
    const uint4* __restrict__ rB = (const uint4*)(htab + i1 * D);
    uint4 A = rA[lane];
    uint4 B = rB[lane];

    float p = dot8_f16(A, B, 0.0f);

    // 3-level xor butterfly: all 8 lanes end with the same bits (allreduce).
    #pragma unroll
    for (int m = 1; m < 8; m <<= 1) p += __shfl_xor(p, m, 8);

    float d1 = dnorm[i0];
    float d2 = dnorm[i1];
    float inv = 1.0f / (d1 * d2);
    float cosv = p * inv;

    if (fabsf(cosv) < TAU) {
        // Borderline: recompute in fp32, bit-identical to the R3 kernel (passed).
        const float4* __restrict__ r0 = (const float4*)(node_embs + (size_t)i0 * D);
        const float4* __restrict__ r1 = (const float4*)(node_embs + (size_t)i1 * D);
        float4 x0 = r0[lane];
        float4 x1 = r0[lane + 8];
        float4 y0 = r1[lane];
        float4 y1 = r1[lane + 8];
        float pp = ((x0.x * y0.x + x0.y * y0.y) + (x0.z * y0.z + x0.w * y0.w))
                 + ((x1.x * y1.x + x1.y * y1.y) + (x1.z * y1.z + x1.w * y1.w));
        #pragma unroll
        for (int m = 1; m < 8; m <<= 1) pp += __shfl_xor(pp, m, 8);
        cosv = pp / (d1 * d2);
    }

    if (lane == 0) {
        float T = read_temperature(temp_ptr);
        float v = 1.0f / (1.0f + expf(-(cosv / T)));
        out[e] = (v <= 0.5f) ? 0.0f : v;    // straight-through hard threshold
    }
}

// Fallback (ws too small): 8 lanes/edge fp32, inline norms (R3 fallback, passed).
__global__ __launch_bounds__(BLOCK) void edge_kernel_fused(
    const float* __restrict__ node_embs,
    const int*   __restrict__ edge_index,
    const int*   __restrict__ temp_ptr,
    float*       __restrict__ out,
    int n_edges)
{
    int t    = blockIdx.x * BLOCK + threadIdx.x;
    int e    = t >> 3;
    int lane = threadIdx.x & 7;
    if (e >= n_edges) return;

    int i0 = edge_index[e];
    int i1 = edge_index[n_edges + e];

    const float4* __restrict__ r0 = (const float4*)(node_embs + (size_t)i0 * D);
    const float4* __restrict__ r1 = (const float4*)(node_embs + (size_t)i1 * D);

    float4 x0 = r0[lane];
    float4 x1 = r0[lane + 8];
    float4 y0 = r1[lane];
    float4 y1 = r1[lane + 8];

    float p  = ((x0.x * y0.x + x0.y * y0.y) + (x0.z * y0.z + x0.w * y0.w))
             + ((x1.x * y1.x + x1.y * y1.y) + (x1.z * y1.z + x1.w * y1.w));
    float a  = ((x0.x * x0.x + x0.y * x0.y) + (x0.z * x0.z + x0.w * x0.w))
             + ((x1.x * x1.x + x1.y * x1.y) + (x1.z * x1.z + x1.w * x1.w));
    float b  = ((y0.x * y0.x + y0.y * y0.y) + (y0.z * y0.z + y0.w * y0.w))
             + ((y1.x * y1.x + y1.y * y1.y) + (y1.z * y1.z + y1.w * y1.w));

    #pragma unroll
    for (int m = 1; m < 8; m <<= 1) {
        p += __shfl_xor(p, m, 8);
        a += __shfl_xor(a, m, 8);
        b += __shfl_xor(b, m, 8);
    }

    if (lane == 0) {
        float T    = read_temperature(temp_ptr);
        float d1   = fmaxf(sqrtf(a), COS_EPS);
        float d2   = fmaxf(sqrtf(b), COS_EPS);
        float cosv = p / (d1 * d2);
        float v    = 1.0f / (1.0f + expf(-(cosv / T)));
        out[e] = (v <= 0.5f) ? 0.0f : v;
    }
}

extern "C" void kernel_launch(void* const* d_in, const int* in_sizes, int n_in,
                              void* d_out, int out_size, void* d_ws, size_t ws_size,
                              hipStream_t stream) {
    const float* node_embs  = (const float*)d_in[0];
    const int*   edge_index = (const int*)d_in[1];
    const int*   temp_ptr   = (const int*)d_in[2];
    float*       out        = (float*)d_out;

    int n_nodes = in_sizes[0] / D;      // node_embs is [N, 64]
    int n_elems = in_sizes[0];
    int n_edges = in_sizes[1] / 2;      // edge_index is [2, E]

    size_t htab_bytes = (size_t)n_elems * sizeof(__half);       // 12.8 MB
    size_t need = htab_bytes + (size_t)n_nodes * sizeof(float); // + 400 KB

    long long edge_threads = (long long)n_edges * 8;
    int grid_e = (int)((edge_threads + BLOCK - 1) / BLOCK);

    if (ws_size >= need) {
        __half* htab = (__half*)d_ws;
        float*  dnorm = (float*)((char*)d_ws + htab_bytes);

        int grid_q = (n_elems / 8 + BLOCK - 1) / BLOCK;
        quant_kernel<<<grid_q, BLOCK, 0, stream>>>(node_embs, htab, n_elems);

        int grid_n = (n_nodes + BLOCK - 1) / BLOCK;
        node_norm_kernel<<<grid_n, BLOCK, 0, stream>>>(node_embs, dnorm, n_nodes);

        GraphLearner_68513318306086_kernel<<<grid_e, BLOCK, 0, stream>>>(
            node_embs, htab, edge_index, dnorm, temp_ptr, out, n_edges);
    } else {
        edge_kernel_fused<<<grid_e, BLOCK, 0, stream>>>(
            node_embs, edge_index, temp_ptr, out, n_edges);
    }
}

// Round 6
// 153.106 us; speedup vs baseline: 1.3226x; 1.0187x over previous
//
#include <hip/hip_runtime.h>
#include <hip/hip_fp16.h>
#include <math.h>

// GraphLearner: per-edge cosine similarity + sigmoid + straight-through threshold.
//   out[e] = let v = sigmoid(cos(f1,f2)/T) in (v <= 0.5 ? 0 : v)
//
// R6 design (R5 post-mortem: edge kernel no longer at the L2-miss-fill ceiling
// — VALUBusy 64%, fill rate dropped to 2.9 TB/s vs R3's 3.6. Slim the VALU):
//  - Kernel N: per-node clamped fp32 norm, numpy stride-8 pairwise order —
//    BIT-EXACT vs np reference (proven by R2 absmax=0.0). Unchanged.
//  - Kernel Q: normalize + quantize: htab[n][i] = fp16(x[n][i] / dnorm[n]).
//    The edge dot of normalized rows IS the cosine: no dnorm gathers, no
//    divides in the edge kernel. |cos error| <= ~1e-3 (Cauchy-Schwarz), well
//    under TAU=6e-3.
//  - Kernel E: 8 lanes/edge, one 128 B line per row. fdot2 fp32-accum dot,
//    3-level xor allreduce. |cos| < TAU -> recompute fp32 bit-identical to R3
//    (node_embs + exact dnorm). Epilogue: hard-threshold gate decided on the
//    SIGN of x (exact; v<=0.5 <=> x<=0) — never on approximate v, since a
//    1-ulp rcp near v=0.5 would flip the gate. Value path uses v_exp/v_rcp
//    (~1e-7 err, only used when x>0 where tolerance is 1.46e-2).

#define D 64
#define BLOCK 256
#define COS_EPS 1e-6f
#define TAU 6e-3f
#define LOG2E 1.4426950408889634f

#define FMA4(A, X, Y) \
    A.x += X.x * Y.x; A.y += X.y * Y.y; A.z += X.z * Y.z; A.w += X.w * Y.w;

#define PAIRWISE8(E, O) \
    (((E.x + E.y) + (E.z + E.w)) + ((O.x + O.y) + (O.z + O.w)))

typedef _Float16 half2_t __attribute__((ext_vector_type(2)));

__device__ __forceinline__ half2_t as_h2(unsigned u) {
    union { unsigned u; half2_t v; } c; c.u = u; return c.v;
}

__device__ __forceinline__ float dot8_f16(uint4 A, uint4 B, float acc) {
#if __has_builtin(__builtin_amdgcn_fdot2)
    acc = __builtin_amdgcn_fdot2(as_h2(A.x), as_h2(B.x), acc, false);
    acc = __builtin_amdgcn_fdot2(as_h2(A.y), as_h2(B.y), acc, false);
    acc = __builtin_amdgcn_fdot2(as_h2(A.z), as_h2(B.z), acc, false);
    acc = __builtin_amdgcn_fdot2(as_h2(A.w), as_h2(B.w), acc, false);
#else
    const __half2* a = (const __half2*)&A;
    const __half2* b = (const __half2*)&B;
    #pragma unroll
    for (int i = 0; i < 4; ++i) {
        float2 af = __half22float2(a[i]);
        float2 bf = __half22float2(b[i]);
        acc = fmaf(af.x, bf.x, acc);
        acc = fmaf(af.y, bf.y, acc);
    }
#endif
    return acc;
}

__device__ __forceinline__ float read_temperature(const int* temp_ptr) {
    int tbits = *temp_ptr;
    if (tbits >= 1 && tbits < (1 << 23)) return (float)tbits;  // int32 temperature
    union { int i; float f; } u; u.i = tbits; return u.f;      // float32 bits
}

// Kernel N: per-node clamped norm, numpy accumulation order (bit-exact).
__global__ __launch_bounds__(BLOCK) void node_norm_kernel(
    const float* __restrict__ node_embs,
    float*       __restrict__ dnorm,
    int n_nodes)
{
    int n = blockIdx.x * BLOCK + threadIdx.x;
    if (n >= n_nodes) return;

    const float4* __restrict__ r = (const float4*)(node_embs + (size_t)n * D);
    float4 z = make_float4(0.f, 0.f, 0.f, 0.f);
    float4 aE = z, aO = z;   // stride-8 accumulators (numpy pairwise order)
    #pragma unroll
    for (int k = 0; k < D / 4; k += 2) {
        float4 x0 = r[k];
        float4 x1 = r[k + 1];
        FMA4(aE, x0, x0)
        FMA4(aO, x1, x1)
    }
    float s = PAIRWISE8(aE, aO);
    dnorm[n] = fmaxf(sqrtf(s), COS_EPS);
}

// Kernel Q: normalized fp16 table. One thread per 8 consecutive elements
// (all 8 belong to one node since 8 | 64).
__global__ __launch_bounds__(BLOCK) void normquant_kernel(
    const float* __restrict__ in,
    const float* __restrict__ dnorm,
    __half*      __restrict__ htab,
    int n_elems)
{
    int t = blockIdx.x * BLOCK + threadIdx.x;
    int base = t * 8;
    if (base >= n_elems) return;
    float inv = 1.0f / dnorm[t >> 3];   // node id = base / 64 = t / 8
    const float4* p = (const float4*)(in + base);
    float4 a = p[0];
    float4 b = p[1];
    __half2 h[4];
    h[0] = __floats2half2_rn(a.x * inv, a.y * inv);
    h[1] = __floats2half2_rn(a.z * inv, a.w * inv);
    h[2] = __floats2half2_rn(b.x * inv, b.y * inv);
    h[3] = __floats2half2_rn(b.z * inv, b.w * inv);
    *(uint4*)(htab + base) = *(const uint4*)h;
}

// Kernel E: 8 lanes/edge over the normalized fp16 table.
__global__ __launch_bounds__(BLOCK) void GraphLearner_68513318306086_kernel(
    const float* __restrict__ node_embs,
    const __half* __restrict__ htab,
    const int*   __restrict__ edge_index,
    const float* __restrict__ dnorm,
    const int*   __restrict__ temp_ptr,
    float*       __restrict__ out,
    int n_edges)
{
    int t    = blockIdx.x * BLOCK + threadIdx.x;
    int e    = t >> 3;              // 8 lanes per edge
    int lane = threadIdx.x & 7;
    if (e >= n_edges) return;

    int i0 = edge_index[e];
    int i1 = edge_index[n_edges + e];

    // normalized fp16 row = 128 B = one cache line; lane loads chunk (16 B).
    const uint4* __restrict__ tab = (const uint4*)htab;
    uint4 A = tab[(i0 << 3) + lane];
    uint4 B = tab[(i1 << 3) + lane];

    float p = dot8_f16(A, B, 0.0f);     // == cosine (rows pre-normalized)

    // 3-level xor butterfly allreduce across the 8-lane group.
    #pragma unroll
    for (int m = 1; m < 8; m <<= 1) p += __shfl_xor(p, m, 8);

    float cosv = p;
    if (fabsf(cosv) < TAU) {
        // Borderline: recompute in fp32, bit-identical to the R3 kernel (passed).
        const float4* __restrict__ r0 = (const float4*)(node_embs + (size_t)i0 * D);
        const float4* __restrict__ r1 = (const float4*)(node_embs + (size_t)i1 * D);
        float4 x0 = r0[lane];
        float4 x1 = r0[lane + 8];
        float4 y0 = r1[lane];
        float4 y1 = r1[lane + 8];
        float pp = ((x0.x * y0.x + x0.y * y0.y) + (x0.z * y0.z + x0.w * y0.w))
                 + ((x1.x * y1.x + x1.y * y1.y) + (x1.z * y1.z + x1.w * y1.w));
        #pragma unroll
        for (int m = 1; m < 8; m <<= 1) pp += __shfl_xor(pp, m, 8);
        cosv = pp / (dnorm[i0] * dnorm[i1]);
    }

    if (lane == 0) {
        float T    = read_temperature(temp_ptr);
        float invT = __builtin_amdgcn_rcpf(T);      // T=1 -> exactly 1.0
        float x    = cosv * invT;
        // Gate on sign(x): v<=0.5 <=> x<=0 exactly (sigmoid(0)=0.5, monotone).
        // Value path may be approximate (~1e-7) — only used when x>0.
        float ex   = __builtin_amdgcn_exp2f(-x * LOG2E);
        float v    = __builtin_amdgcn_rcpf(1.0f + ex);
        out[e] = (x <= 0.0f) ? 0.0f : v;
    }
}

// Fallback (ws too small): 8 lanes/edge fp32, inline norms (R3 fallback, passed).
__global__ __launch_bounds__(BLOCK) void edge_kernel_fused(
    const float* __restrict__ node_embs,
    const int*   __restrict__ edge_index,
    const int*   __restrict__ temp_ptr,
    float*       __restrict__ out,
    int n_edges)
{
    int t    = blockIdx.x * BLOCK + threadIdx.x;
    int e    = t >> 3;
    int lane = threadIdx.x & 7;
    if (e >= n_edges) return;

    int i0 = edge_index[e];
    int i1 = edge_index[n_edges + e];

    const float4* __restrict__ r0 = (const float4*)(node_embs + (size_t)i0 * D);
    const float4* __restrict__ r1 = (const float4*)(node_embs + (size_t)i1 * D);

    float4 x0 = r0[lane];
    float4 x1 = r0[lane + 8];
    float4 y0 = r1[lane];
    float4 y1 = r1[lane + 8];

    float p  = ((x0.x * y0.x + x0.y * y0.y) + (x0.z * y0.z + x0.w * y0.w))
             + ((x1.x * y1.x + x1.y * y1.y) + (x1.z * y1.z + x1.w * y1.w));
    float a  = ((x0.x * x0.x + x0.y * x0.y) + (x0.z * x0.z + x0.w * x0.w))
             + ((x1.x * x1.x + x1.y * x1.y) + (x1.z * x1.z + x1.w * x1.w));
    float b  = ((y0.x * y0.x + y0.y * y0.y) + (y0.z * y0.z + y0.w * y0.w))
             + ((y1.x * y1.x + y1.y * y1.y) + (y1.z * y1.z + y1.w * y1.w));

    #pragma unroll
    for (int m = 1; m < 8; m <<= 1) {
        p += __shfl_xor(p, m, 8);
        a += __shfl_xor(a, m, 8);
        b += __shfl_xor(b, m, 8);
    }

    if (lane == 0) {
        float T    = read_temperature(temp_ptr);
        float d1   = fmaxf(sqrtf(a), COS_EPS);
        float d2   = fmaxf(sqrtf(b), COS_EPS);
        float cosv = p / (d1 * d2);
        float v    = 1.0f / (1.0f + expf(-(cosv / T)));
        out[e] = (v <= 0.5f) ? 0.0f : v;
    }
}

extern "C" void kernel_launch(void* const* d_in, const int* in_sizes, int n_in,
                              void* d_out, int out_size, void* d_ws, size_t ws_size,
                              hipStream_t stream) {
    const float* node_embs  = (const float*)d_in[0];
    const int*   edge_index = (const int*)d_in[1];
    const int*   temp_ptr   = (const int*)d_in[2];
    float*       out        = (float*)d_out;

    int n_nodes = in_sizes[0] / D;      // node_embs is [N, 64]
    int n_elems = in_sizes[0];
    int n_edges = in_sizes[1] / 2;      // edge_index is [2, E]

    size_t htab_bytes = (size_t)n_elems * sizeof(__half);       // 12.8 MB
    size_t need = htab_bytes + (size_t)n_nodes * sizeof(float); // + 400 KB

    long long edge_threads = (long long)n_edges * 8;
    int grid_e = (int)((edge_threads + BLOCK - 1) / BLOCK);

    if (ws_size >= need) {
        __half* htab  = (__half*)d_ws;
        float*  dnorm = (float*)((char*)d_ws + htab_bytes);

        int grid_n = (n_nodes + BLOCK - 1) / BLOCK;
        node_norm_kernel<<<grid_n, BLOCK, 0, stream>>>(node_embs, dnorm, n_nodes);

        int grid_q = (n_elems / 8 + BLOCK - 1) / BLOCK;
        normquant_kernel<<<grid_q, BLOCK, 0, stream>>>(node_embs, dnorm, htab, n_elems);

        GraphLearner_68513318306086_kernel<<<grid_e, BLOCK, 0, stream>>>(
            node_embs, htab, edge_index, dnorm, temp_ptr, out, n_edges);
    } else {
        edge_kernel_fused<<<grid_e, BLOCK, 0, stream>>>(
            node_embs, edge_index, temp_ptr, out, n_edges);
    }
}

// Round 7
// 150.776 us; speedup vs baseline: 1.3430x; 1.0155x over previous
//
#include <hip/hip_runtime.h>
#include <hip/hip_fp16.h>
#include <math.h>

// GraphLearner: per-edge cosine similarity + sigmoid + straight-through threshold.
//   out[e] = let v = sigmoid(cos(f1,f2)/T) in (v <= 0.5 ? 0 : v)
//
// R7 design (R6 post-mortem: edge kernel within ~12% of the ~3.6-3.7 TB/s
// random-gather L2-fill ceiling — R3 saturated it at 440 MB, R4's 2x MLP was
// neutral, R6 runs at 3.45 TB/s with VALU at 37%. Remaining waste is the
// two-pass preprocessing):
//  - Kernel P (merged): one thread per node — read the fp32 row ONCE, compute
//    the clamped norm in numpy stride-8 pairwise order (BIT-EXACT vs np ref,
//    proven by R2 absmax=0.0), write dnorm[n] and the normalized fp16 row.
//    Saves a full 25.6 MB re-read + one launch vs R6's separate norm+quant.
//  - Kernel E (unchanged from R6): 8 lanes/edge, normalized fp16 row = 128 B =
//    one cache line; fdot2 fp32-accum dot == cosine; 3-level xor allreduce;
//    |cos| < TAU=6e-3 -> fp32 recompute bit-identical to R3 (passed).
//    Epilogue gates the hard threshold on the SIGN of x (exact), value path
//    uses v_exp/v_rcp (~1e-7 err, only where tolerance is 1.46e-2).

#define D 64
#define BLOCK 256
#define COS_EPS 1e-6f
#define TAU 6e-3f
#define LOG2E 1.4426950408889634f

#define FMA4(A, X, Y) \
    A.x += X.x * Y.x; A.y += X.y * Y.y; A.z += X.z * Y.z; A.w += X.w * Y.w;

#define PAIRWISE8(E, O) \
    (((E.x + E.y) + (E.z + E.w)) + ((O.x + O.y) + (O.z + O.w)))

typedef _Float16 half2_t __attribute__((ext_vector_type(2)));

__device__ __forceinline__ half2_t as_h2(unsigned u) {
    union { unsigned u; half2_t v; } c; c.u = u; return c.v;
}

__device__ __forceinline__ float dot8_f16(uint4 A, uint4 B, float acc) {
#if __has_builtin(__builtin_amdgcn_fdot2)
    acc = __builtin_amdgcn_fdot2(as_h2(A.x), as_h2(B.x), acc, false);
    acc = __builtin_amdgcn_fdot2(as_h2(A.y), as_h2(B.y), acc, false);
    acc = __builtin_amdgcn_fdot2(as_h2(A.z), as_h2(B.z), acc, false);
    acc = __builtin_amdgcn_fdot2(as_h2(A.w), as_h2(B.w), acc, false);
#else
    const __half2* a = (const __half2*)&A;
    const __half2* b = (const __half2*)&B;
    #pragma unroll
    for (int i = 0; i < 4; ++i) {
        float2 af = __half22float2(a[i]);
        float2 bf = __half22float2(b[i]);
        acc = fmaf(af.x, bf.x, acc);
        acc = fmaf(af.y, bf.y, acc);
    }
#endif
    return acc;
}

__device__ __forceinline__ float read_temperature(const int* temp_ptr) {
    int tbits = *temp_ptr;
    if (tbits >= 1 && tbits < (1 << 23)) return (float)tbits;  // int32 temperature
    union { int i; float f; } u; u.i = tbits; return u.f;      // float32 bits
}

// Kernel P: fused per-node norm (bit-exact numpy order) + normalized fp16 row.
__global__ __launch_bounds__(BLOCK) void node_prep_kernel(
    const float* __restrict__ node_embs,
    float*       __restrict__ dnorm,
    __half*      __restrict__ htab,
    int n_nodes)
{
    int n = blockIdx.x * BLOCK + threadIdx.x;
    if (n >= n_nodes) return;

    const float4* __restrict__ r = (const float4*)(node_embs + (size_t)n * D);

    // Read the full row once into registers (16 float4s = 64 floats).
    float4 row[16];
    #pragma unroll
    for (int k = 0; k < 16; ++k) row[k] = r[k];

    // Bit-exact numpy stride-8 pairwise sumsq (same order as R2/R3, absmax=0.0).
    float4 z = make_float4(0.f, 0.f, 0.f, 0.f);
    float4 aE = z, aO = z;
    #pragma unroll
    for (int k = 0; k < 16; k += 2) {
        FMA4(aE, row[k], row[k])
        FMA4(aO, row[k + 1], row[k + 1])
    }
    float s = PAIRWISE8(aE, aO);
    float d = fmaxf(sqrtf(s), COS_EPS);
    dnorm[n] = d;

    // Normalized fp16 row (8 uint4 stores = 128 B).
    float inv = 1.0f / d;
    uint4* dst = (uint4*)(htab + (size_t)n * D);
    #pragma unroll
    for (int k = 0; k < 16; k += 2) {
        float4 a = row[k];
        float4 b = row[k + 1];
        __half2 h[4];
        h[0] = __floats2half2_rn(a.x * inv, a.y * inv);
        h[1] = __floats2half2_rn(a.z * inv, a.w * inv);
        h[2] = __floats2half2_rn(b.x * inv, b.y * inv);
        h[3] = __floats2half2_rn(b.z * inv, b.w * inv);
        dst[k >> 1] = *(const uint4*)h;
    }
}

// Kernel E: 8 lanes/edge over the normalized fp16 table.
__global__ __launch_bounds__(BLOCK) void GraphLearner_68513318306086_kernel(
    const float* __restrict__ node_embs,
    const __half* __restrict__ htab,
    const int*   __restrict__ edge_index,
    const float* __restrict__ dnorm,
    const int*   __restrict__ temp_ptr,
    float*       __restrict__ out,
    int n_edges)
{
    int t    = blockIdx.x * BLOCK + threadIdx.x;
    int e    = t >> 3;              // 8 lanes per edge
    int lane = threadIdx.x & 7;
    if (e >= n_edges) return;

    int i0 = edge_index[e];
    int i1 = edge_index[n_edges + e];

    // normalized fp16 row = 128 B = one cache line; lane loads chunk (16 B).
    const uint4* __restrict__ tab = (const uint4*)htab;
    uint4 A = tab[(i0 << 3) + lane];
    uint4 B = tab[(i1 << 3) + lane];

    float p = dot8_f16(A, B, 0.0f);     // == cosine (rows pre-normalized)

    // 3-level xor butterfly allreduce across the 8-lane group.
    #pragma unroll
    for (int m = 1; m < 8; m <<= 1) p += __shfl_xor(p, m, 8);

    float cosv = p;
    if (fabsf(cosv) < TAU) {
        // Borderline: recompute in fp32, bit-identical to the R3 kernel (passed).
        const float4* __restrict__ r0 = (const float4*)(node_embs + (size_t)i0 * D);
        const float4* __restrict__ r1 = (const float4*)(node_embs + (size_t)i1 * D);
        float4 x0 = r0[lane];
        float4 x1 = r0[lane + 8];
        float4 y0 = r1[lane];
        float4 y1 = r1[lane + 8];
        float pp = ((x0.x * y0.x + x0.y * y0.y) + (x0.z * y0.z + x0.w * y0.w))
                 + ((x1.x * y1.x + x1.y * y1.y) + (x1.z * y1.z + x1.w * y1.w));
        #pragma unroll
        for (int m = 1; m < 8; m <<= 1) pp += __shfl_xor(pp, m, 8);
        cosv = pp / (dnorm[i0] * dnorm[i1]);
    }

    if (lane == 0) {
        float T    = read_temperature(temp_ptr);
        float invT = __builtin_amdgcn_rcpf(T);      // T=1 -> exactly 1.0
        float x    = cosv * invT;
        // Gate on sign(x): v<=0.5 <=> x<=0 exactly (sigmoid(0)=0.5, monotone).
        // Value path may be approximate (~1e-7) — only used when x>0.
        float ex   = __builtin_amdgcn_exp2f(-x * LOG2E);
        float v    = __builtin_amdgcn_rcpf(1.0f + ex);
        out[e] = (x <= 0.0f) ? 0.0f : v;
    }
}

// Fallback (ws too small): 8 lanes/edge fp32, inline norms (R3 fallback, passed).
__global__ __launch_bounds__(BLOCK) void edge_kernel_fused(
    const float* __restrict__ node_embs,
    const int*   __restrict__ edge_index,
    const int*   __restrict__ temp_ptr,
    float*       __restrict__ out,
    int n_edges)
{
    int t    = blockIdx.x * BLOCK + threadIdx.x;
    int e    = t >> 3;
    int lane = threadIdx.x & 7;
    if (e >= n_edges) return;

    int i0 = edge_index[e];
    int i1 = edge_index[n_edges + e];

    const float4* __restrict__ r0 = (const float4*)(node_embs + (size_t)i0 * D);
    const float4* __restrict__ r1 = (const float4*)(node_embs + (size_t)i1 * D);

    float4 x0 = r0[lane];
    float4 x1 = r0[lane + 8];
    float4 y0 = r1[lane];
    float4 y1 = r1[lane + 8];

    float p  = ((x0.x * y0.x + x0.y * y0.y) + (x0.z * y0.z + x0.w * y0.w))
             + ((x1.x * y1.x + x1.y * y1.y) + (x1.z * y1.z + x1.w * y1.w));
    float a  = ((x0.x * x0.x + x0.y * x0.y) + (x0.z * x0.z + x0.w * x0.w))
             + ((x1.x * x1.x + x1.y * x1.y) + (x1.z * x1.z + x1.w * x1.w));
    float b  = ((y0.x * y0.x + y0.y * y0.y) + (y0.z * y0.z + y0.w * y0.w))
             + ((y1.x * y1.x + y1.y * y1.y) + (y1.z * y1.z + y1.w * y1.w));

    #pragma unroll
    for (int m = 1; m < 8; m <<= 1) {
        p += __shfl_xor(p, m, 8);
        a += __shfl_xor(a, m, 8);
        b += __shfl_xor(b, m, 8);
    }

    if (lane == 0) {
        float T    = read_temperature(temp_ptr);
        float d1   = fmaxf(sqrtf(a), COS_EPS);
        float d2   = fmaxf(sqrtf(b), COS_EPS);
        float cosv = p / (d1 * d2);
        float v    = 1.0f / (1.0f + expf(-(cosv / T)));
        out[e] = (v <= 0.5f) ? 0.0f : v;
    }
}

extern "C" void kernel_launch(void* const* d_in, const int* in_sizes, int n_in,
                              void* d_out, int out_size, void* d_ws, size_t ws_size,
                              hipStream_t stream) {
    const float* node_embs  = (const float*)d_in[0];
    const int*   edge_index = (const int*)d_in[1];
    const int*   temp_ptr   = (const int*)d_in[2];
    float*       out        = (float*)d_out;

    int n_nodes = in_sizes[0] / D;      // node_embs is [N, 64]
    int n_elems = in_sizes[0];
    int n_edges = in_sizes[1] / 2;      // edge_index is [2, E]

    size_t htab_bytes = (size_t)n_elems * sizeof(__half);       // 12.8 MB
    size_t need = htab_bytes + (size_t)n_nodes * sizeof(float); // + 400 KB

    long long edge_threads = (long long)n_edges * 8;
    int grid_e = (int)((edge_threads + BLOCK - 1) / BLOCK);

    if (ws_size >= need) {
        __half* htab  = (__half*)d_ws;
        float*  dnorm = (float*)((char*)d_ws + htab_bytes);

        int grid_n = (n_nodes + BLOCK - 1) / BLOCK;
        node_prep_kernel<<<grid_n, BLOCK, 0, stream>>>(node_embs, dnorm, htab, n_nodes);

        GraphLearner_68513318306086_kernel<<<grid_e, BLOCK, 0, stream>>>(
            node_embs, htab, edge_index, dnorm, temp_ptr, out, n_edges);
    } else {
        edge_kernel_fused<<<grid_e, BLOCK, 0, stream>>>(
            node_embs, edge_index, temp_ptr, out, n_edges);
    }
}

// Round 8
// 145.245 us; speedup vs baseline: 1.3942x; 1.0381x over previous
//
#include <hip/hip_runtime.h>
#include <hip/hip_fp16.h>
#include <math.h>

// GraphLearner: per-edge cosine similarity + sigmoid + straight-through threshold.
//   out[e] = let v = sigmoid(cos(f1,f2)/T) in (v <= 0.5 ? 0 : v)
//
// R8 design (R7 post-mortem: edge kernel at 66 µs / 3.45 TB/s fill vs R3's
// demonstrated 3.7 TB/s. R7's wave has only 16 lines in flight (2 gather
// instrs) vs R3's 32 — restore flight depth by processing 2 edges per 8-lane
// group; R4 proved this neutral only at an already-saturated 3.7 TB/s):
//  - Kernel P: one thread per node — read fp32 row once, clamped norm in
//    numpy stride-8 pairwise order (BIT-EXACT vs np ref, R2 absmax=0.0),
//    write dnorm[n] + normalized fp16 row (row = 128 B = one cache line).
//  - Kernel E: 8 lanes per 2-EDGE group. int2 index loads cover both edges;
//    4 uint4 gathers issue back-to-back (32 lines/wave in flight). fdot2
//    fp32-accum dot == cosine. |cos| < TAU=6e-3 -> fp32 recompute
//    bit-identical to R3 (passed). Hard-threshold gate on SIGN of x (exact);
//    value path v_exp/v_rcp (~1e-7, only where tolerance is 1.46e-2).

#define D 64
#define BLOCK 256
#define COS_EPS 1e-6f
#define TAU 6e-3f
#define LOG2E 1.4426950408889634f

#define FMA4(A, X, Y) \
    A.x += X.x * Y.x; A.y += X.y * Y.y; A.z += X.z * Y.z; A.w += X.w * Y.w;

#define PAIRWISE8(E, O) \
    (((E.x + E.y) + (E.z + E.w)) + ((O.x + O.y) + (O.z + O.w)))

typedef _Float16 half2_t __attribute__((ext_vector_type(2)));

__device__ __forceinline__ half2_t as_h2(unsigned u) {
    union { unsigned u; half2_t v; } c; c.u = u; return c.v;
}

__device__ __forceinline__ float dot8_f16(uint4 A, uint4 B, float acc) {
#if __has_builtin(__builtin_amdgcn_fdot2)
    acc = __builtin_amdgcn_fdot2(as_h2(A.x), as_h2(B.x), acc, false);
    acc = __builtin_amdgcn_fdot2(as_h2(A.y), as_h2(B.y), acc, false);
    acc = __builtin_amdgcn_fdot2(as_h2(A.z), as_h2(B.z), acc, false);
    acc = __builtin_amdgcn_fdot2(as_h2(A.w), as_h2(B.w), acc, false);
#else
    const __half2* a = (const __half2*)&A;
    const __half2* b = (const __half2*)&B;
    #pragma unroll
    for (int i = 0; i < 4; ++i) {
        float2 af = __half22float2(a[i]);
        float2 bf = __half22float2(b[i]);
        acc = fmaf(af.x, bf.x, acc);
        acc = fmaf(af.y, bf.y, acc);
    }
#endif
    return acc;
}

__device__ __forceinline__ float read_temperature(const int* temp_ptr) {
    int tbits = *temp_ptr;
    if (tbits >= 1 && tbits < (1 << 23)) return (float)tbits;  // int32 temperature
    union { int i; float f; } u; u.i = tbits; return u.f;      // float32 bits
}

// Exact fp32 recompute for one edge, bit-identical to the R3 kernel (passed).
__device__ __forceinline__ float exact_cos(
    const float* __restrict__ node_embs,
    const float* __restrict__ dnorm,
    int i0, int i1, int lane)
{
    const float4* __restrict__ r0 = (const float4*)(node_embs + (size_t)i0 * D);
    const float4* __restrict__ r1 = (const float4*)(node_embs + (size_t)i1 * D);
    float4 x0 = r0[lane];
    float4 x1 = r0[lane + 8];
    float4 y0 = r1[lane];
    float4 y1 = r1[lane + 8];
    float pp = ((x0.x * y0.x + x0.y * y0.y) + (x0.z * y0.z + x0.w * y0.w))
             + ((x1.x * y1.x + x1.y * y1.y) + (x1.z * y1.z + x1.w * y1.w));
    #pragma unroll
    for (int m = 1; m < 8; m <<= 1) pp += __shfl_xor(pp, m, 8);
    return pp / (dnorm[i0] * dnorm[i1]);
}

// Kernel P: fused per-node norm (bit-exact numpy order) + normalized fp16 row.
__global__ __launch_bounds__(BLOCK) void node_prep_kernel(
    const float* __restrict__ node_embs,
    float*       __restrict__ dnorm,
    __half*      __restrict__ htab,
    int n_nodes)
{
    int n = blockIdx.x * BLOCK + threadIdx.x;
    if (n >= n_nodes) return;

    const float4* __restrict__ r = (const float4*)(node_embs + (size_t)n * D);

    float4 row[16];
    #pragma unroll
    for (int k = 0; k < 16; ++k) row[k] = r[k];

    float4 z = make_float4(0.f, 0.f, 0.f, 0.f);
    float4 aE = z, aO = z;
    #pragma unroll
    for (int k = 0; k < 16; k += 2) {
        FMA4(aE, row[k], row[k])
        FMA4(aO, row[k + 1], row[k + 1])
    }
    float s = PAIRWISE8(aE, aO);
    float d = fmaxf(sqrtf(s), COS_EPS);
    dnorm[n] = d;

    float inv = 1.0f / d;
    uint4* dst = (uint4*)(htab + (size_t)n * D);
    #pragma unroll
    for (int k = 0; k < 16; k += 2) {
        float4 a = row[k];
        float4 b = row[k + 1];
        __half2 h[4];
        h[0] = __floats2half2_rn(a.x * inv, a.y * inv);
        h[1] = __floats2half2_rn(a.z * inv, a.w * inv);
        h[2] = __floats2half2_rn(b.x * inv, b.y * inv);
        h[3] = __floats2half2_rn(b.z * inv, b.w * inv);
        dst[k >> 1] = *(const uint4*)h;
    }
}

// Kernel E: 8 lanes per group, 2 edges per group, fp16 normalized table.
__global__ __launch_bounds__(BLOCK) void GraphLearner_68513318306086_kernel(
    const float* __restrict__ node_embs,
    const __half* __restrict__ htab,
    const int*   __restrict__ edge_index,
    const float* __restrict__ dnorm,
    const int*   __restrict__ temp_ptr,
    float*       __restrict__ out,
    int n_edges)
{
    int t    = blockIdx.x * BLOCK + threadIdx.x;
    int g    = t >> 3;              // group id: edges 2g, 2g+1
    int lane = threadIdx.x & 7;
    int e0   = g * 2;
    if (e0 >= n_edges) return;
    bool has1 = (e0 + 1) < n_edges;

    // One int2 per endpoint row covers both edges (E is even in this workload;
    // scalar fallback for a possible odd tail).
    int2 i0p, i1p;
    if (has1) {
        i0p = *(const int2*)(edge_index + e0);
        i1p = *(const int2*)(edge_index + n_edges + e0);
    } else {
        i0p.x = edge_index[e0];            i0p.y = i0p.x;
        i1p.x = edge_index[n_edges + e0];  i1p.y = i1p.x;
    }

    // 4 gathers back-to-back: 32 distinct 128 B lines in flight per wave.
    const uint4* __restrict__ tab = (const uint4*)htab;
    uint4 A0 = tab[(i0p.x << 3) + lane];
    uint4 B0 = tab[(i1p.x << 3) + lane];
    uint4 A1 = tab[(i0p.y << 3) + lane];
    uint4 B1 = tab[(i1p.y << 3) + lane];

    float p0 = dot8_f16(A0, B0, 0.0f);   // == cosine (rows pre-normalized)
    float p1 = dot8_f16(A1, B1, 0.0f);

    // 3-level xor butterfly allreduce (both edges in parallel).
    #pragma unroll
    for (int m = 1; m < 8; m <<= 1) {
        p0 += __shfl_xor(p0, m, 8);
        p1 += __shfl_xor(p1, m, 8);
    }

    float cos0 = p0;
    float cos1 = p1;
    if (fabsf(cos0) < TAU)
        cos0 = exact_cos(node_embs, dnorm, i0p.x, i1p.x, lane);
    if (has1 && fabsf(cos1) < TAU)
        cos1 = exact_cos(node_embs, dnorm, i0p.y, i1p.y, lane);

    if (lane < 2 && (lane == 0 || has1)) {
        float cosv = lane ? cos1 : cos0;
        float T    = read_temperature(temp_ptr);
        float invT = __builtin_amdgcn_rcpf(T);      // T=1 -> exactly 1.0
        float x    = cosv * invT;
        // Gate on sign(x): v<=0.5 <=> x<=0 exactly (sigmoid monotone, sig(0)=0.5).
        float ex   = __builtin_amdgcn_exp2f(-x * LOG2E);
        float v    = __builtin_amdgcn_rcpf(1.0f + ex);
        out[e0 + lane] = (x <= 0.0f) ? 0.0f : v;
    }
}

// Fallback (ws too small): 8 lanes/edge fp32, inline norms (R3 fallback, passed).
__global__ __launch_bounds__(BLOCK) void edge_kernel_fused(
    const float* __restrict__ node_embs,
    const int*   __restrict__ edge_index,
    const int*   __restrict__ temp_ptr,
    float*       __restrict__ out,
    int n_edges)
{
    int t    = blockIdx.x * BLOCK + threadIdx.x;
    int e    = t >> 3;
    int lane = threadIdx.x & 7;
    if (e >= n_edges) return;

    int i0 = edge_index[e];
    int i1 = edge_index[n_edges + e];

    const float4* __restrict__ r0 = (const float4*)(node_embs + (size_t)i0 * D);
    const float4* __restrict__ r1 = (const float4*)(node_embs + (size_t)i1 * D);

    float4 x0 = r0[lane];
    float4 x1 = r0[lane + 8];
    float4 y0 = r1[lane];
    float4 y1 = r1[lane + 8];

    float p  = ((x0.x * y0.x + x0.y * y0.y) + (x0.z * y0.z + x0.w * y0.w))
             + ((x1.x * y1.x + x1.y * y1.y) + (x1.z * y1.z + x1.w * y1.w));
    float a  = ((x0.x * x0.x + x0.y * x0.y) + (x0.z * x0.z + x0.w * x0.w))
             + ((x1.x * x1.x + x1.y * x1.y) + (x1.z * x1.z + x1.w * x1.w));
    float b  = ((y0.x * y0.x + y0.y * y0.y) + (y0.z * y0.z + y0.w * y0.w))
             + ((y1.x * y1.x + y1.y * y1.y) + (y1.z * y1.z + y1.w * y1.w));

    #pragma unroll
    for (int m = 1; m < 8; m <<= 1) {
        p += __shfl_xor(p, m, 8);
        a += __shfl_xor(a, m, 8);
        b += __shfl_xor(b, m, 8);
    }

    if (lane == 0) {
        float T    = read_temperature(temp_ptr);
        float d1   = fmaxf(sqrtf(a), COS_EPS);
        float d2   = fmaxf(sqrtf(b), COS_EPS);
        float cosv = p / (d1 * d2);
        float v    = 1.0f / (1.0f + expf(-(cosv / T)));
        out[e] = (v <= 0.5f) ? 0.0f : v;
    }
}

extern "C" void kernel_launch(void* const* d_in, const int* in_sizes, int n_in,
                              void* d_out, int out_size, void* d_ws, size_t ws_size,
                              hipStream_t stream) {
    const float* node_embs  = (const float*)d_in[0];
    const int*   edge_index = (const int*)d_in[1];
    const int*   temp_ptr   = (const int*)d_in[2];
    float*       out        = (float*)d_out;

    int n_nodes = in_sizes[0] / D;      // node_embs is [N, 64]
    int n_elems = in_sizes[0];
    int n_edges = in_sizes[1] / 2;      // edge_index is [2, E]

    size_t htab_bytes = (size_t)n_elems * sizeof(__half);       // 12.8 MB
    size_t need = htab_bytes + (size_t)n_nodes * sizeof(float); // + 400 KB

    if (ws_size >= need) {
        __half* htab  = (__half*)d_ws;
        float*  dnorm = (float*)((char*)d_ws + htab_bytes);

        int grid_n = (n_nodes + BLOCK - 1) / BLOCK;
        node_prep_kernel<<<grid_n, BLOCK, 0, stream>>>(node_embs, dnorm, htab, n_nodes);

        int n_groups = (n_edges + 1) / 2;          // 2 edges per 8-lane group
        long long n_threads = (long long)n_groups * 8;
        int grid_e = (int)((n_threads + BLOCK - 1) / BLOCK);
        GraphLearner_68513318306086_kernel<<<grid_e, BLOCK, 0, stream>>>(
            node_embs, htab, edge_index, dnorm, temp_ptr, out, n_edges);
    } else {
        int grid_e = (int)(((long long)n_edges * 8 + BLOCK - 1) / BLOCK);
        edge_kernel_fused<<<grid_e, BLOCK, 0, stream>>>(
            node_embs, edge_index, temp_ptr, out, n_edges);
    }
}